// Round 11
// baseline (103.732 us; speedup 1.0000x reference)
//
#include <hip/hip_runtime.h>
#include <hip/hip_bf16.h>
#include <math.h>

// InfoNCE fused, symmetric-Gram, MX-fp4 (e2m1, fixed 2^-4 scales), single-barrier:
//   prep     : row-normalize z1|z2 -> fp4 U (2 MB), natural k-order, 2 elems/byte
//   gram     : upper-tri 128x128 tiles; FULL-K panels staged once into LDS
//              (64 KB), ONE barrier, then 4 K-tiles of mfma_scale 16x16x128 fp4
//              with no further barriers; exp epilogue -> partials + posdot
//   finalize : nll_i = -10*posdot[i%4096] + ln(sum_j partials[j][i]); mean
#define N2     8192
#define HALF_N 4096
#define DD     512
#define RB     256                 // bytes per row of U (fp4: 512 * 0.5 B)
#define BM     128
#define KBT    64                  // bytes/row per k-tile = K=128 fp4
#define NKT    (RB / KBT)          // 4 k-tiles
#define NB     (N2 / BM)           // 64 block-rows/cols
#define NTRI   (NB * (NB + 1) / 2) // 2080 upper-tri blocks

#define U_BYTES    ((size_t)N2 * RB)          // 2 MB (fp4)
#define PART_BYTES ((size_t)NB * N2 * 4)      // 2 MB
#define PD_BYTES   ((size_t)HALF_N * 4)       // 16 KB

typedef __attribute__((ext_vector_type(4))) float f32x4;
typedef __attribute__((ext_vector_type(4))) int   i32x4;
typedef __attribute__((ext_vector_type(8))) int   i32x8;

#define SCALE_M4 0x7B7B7B7B        // E8M0 123 in every byte -> scale = 2^-4

__device__ __forceinline__ void load16_lds(const void* g, void* l) {
    // async global->LDS DMA, 16 B/lane; LDS dest = wave-uniform base + lane*16
    __builtin_amdgcn_global_load_lds(
        (const __attribute__((address_space(1))) void*)g,
        (__attribute__((address_space(3))) void*)l, 16, 0, 0);
}

// e2m1 RNE encode of t = |x|*16 (values {0,.5,1,1.5,2,3,4,6}), sign in bit 3
__device__ __forceinline__ unsigned enc_fp4(float x) {
    const float t = fabsf(x) * 16.0f;
    unsigned c = (t < 0.25f) ? 0u
               : (t < 0.75f) ? 1u
               : (t < 1.25f) ? 2u
               : (t < 1.75f) ? 3u
               : (t < 2.5f)  ? 4u
               : (t < 3.5f)  ? 5u
               : (t < 5.0f)  ? 6u : 7u;
    return c | (x < 0.0f ? 8u : 0u);
}

// ---------------- prep: normalize rows, emit fp4 (natural k-order) --------
__global__ __launch_bounds__(256) void prep_kernel(
    const float* __restrict__ z1, const float* __restrict__ z2,
    unsigned char* __restrict__ U, float* __restrict__ out)
{
    const int tid = threadIdx.x;
    if (blockIdx.x == 0 && tid == 0) out[0] = 0.0f;   // d_out re-poisoned each call

    const int wave = tid >> 6;
    const int lane = tid & 63;
    const int row  = blockIdx.x * 4 + wave;

    const float* src = (row < HALF_N) ? (z1 + (size_t)row * DD)
                                      : (z2 + (size_t)(row - HALF_N) * DD);
    float4 a = ((const float4*)src)[lane * 2 + 0];
    float4 b = ((const float4*)src)[lane * 2 + 1];
    float ss = a.x*a.x + a.y*a.y + a.z*a.z + a.w*a.w
             + b.x*b.x + b.y*b.y + b.z*b.z + b.w*b.w;
#pragma unroll
    for (int off = 32; off > 0; off >>= 1) ss += __shfl_xor(ss, off);
    const float inv = 1.0f / fmaxf(sqrtf(ss), 1e-8f);

    const float v[8] = {a.x*inv, a.y*inv, a.z*inv, a.w*inv,
                        b.x*inv, b.y*inv, b.z*inv, b.w*inv};
    unsigned pk = 0;
#pragma unroll
    for (int j = 0; j < 8; ++j)
        pk |= enc_fp4(v[j]) << (4 * j);   // elem j -> nibble j (k = lane*8 + j)
    *(unsigned*)(U + (size_t)row * RB + lane * 4) = pk;
}

// ---------------- gram: full-K staged once, ONE barrier, no K-loop sync ----
// LDS kt-major [kt][row][64]; within each 64B group, logical seg s of row r
// lives at slot s^((r>>1)&3) (swizzle via per-lane DMA SOURCE address):
// frag b128 reads exactly 2-way bank-aliased (free), DMA dest contiguous.
__global__ __launch_bounds__(256, 2) void gram_kernel(
    const unsigned char* __restrict__ U, float* __restrict__ partials,
    float* __restrict__ posdot)
{
    __shared__ unsigned char Ash[NKT][BM][KBT];   // 32 KB
    __shared__ unsigned char Bsh[NKT][BM][KBT];   // 32 KB
    __shared__ float racc[2][BM];                 // [wc][row] — unique writers
    __shared__ float cacc[2][BM];                 // [wr][col] — unique writers

    const int tid  = threadIdx.x;
    const int wave = tid >> 6;
    const int lane = tid & 63;

    // linear block id -> (by, bx), by <= bx ; t0(by) = by*(129-by)/2
    const int t = blockIdx.x;
    int by = (int)((129.0 - sqrt(16641.0 - 8.0 * (double)t)) * 0.5);
    by = min(max(by, 0), NB - 1);
    while (by > 0       && t <  (by * (129 - by)) / 2) --by;
    while (by < NB - 1  && t >= ((by + 1) * (128 - by)) / 2) ++by;
    const int bx = by + (t - (by * (129 - by)) / 2);

    const int wr = wave >> 1;            // row half (0/1)
    const int wc = wave & 1;             // col half (0/1)
    const size_t arow0 = (size_t)by * BM;
    const size_t brow0 = (size_t)bx * BM;

    // staging: chunk = 16 rows x 64 B = one wave-DMA (1 KB); per kt: 8 chunks
    // per array, 2 per wave; all 4 kts staged up-front (16 DMAs/lane total)
    const int sseg = (lane & 3) ^ ((lane >> 3) & 3);   // source seg for swizzled slot
    {
        const int lr = lane >> 2;                      // row within chunk
#pragma unroll
        for (int kt = 0; kt < NKT; ++kt) {
            const int k0 = kt * KBT;
#pragma unroll
            for (int hh = 0; hh < 2; ++hh) {
                const int c = wave * 2 + hh;           // chunk 0..7
                const int r = c * 16 + lr;
                load16_lds(U + (arow0 + r) * RB + k0 + sseg * 16,
                           &Ash[kt][c * 16][0]);
                load16_lds(U + (brow0 + r) * RB + k0 + sseg * 16,
                           &Bsh[kt][c * 16][0]);
            }
        }
    }

    f32x4 acc[4][4];
#pragma unroll
    for (int i = 0; i < 4; ++i)
#pragma unroll
        for (int j = 0; j < 4; ++j) acc[i][j] = (f32x4){0.f, 0.f, 0.f, 0.f};

    const int fr   = lane & 15;
    const int quad = lane >> 4;
    const int sb   = (quad ^ ((fr >> 1) & 3)) * 16;  // swizzled seg byte offset

    __syncthreads();   // the ONLY pre-epilogue barrier: drains all staging DMA

#pragma unroll
    for (int kt = 0; kt < NKT; ++kt) {
        i32x8 af[4], bfr[4];
#pragma unroll
        for (int tt = 0; tt < 4; ++tt) {
            i32x4 a4 = *(const i32x4*)&Ash[kt][wr * 64 + tt * 16 + fr][sb];
            i32x4 b4 = *(const i32x4*)&Bsh[kt][wc * 64 + tt * 16 + fr][sb];
            af[tt]  = __builtin_shufflevector(a4, a4, 0, 1, 2, 3, 0, 1, 2, 3);
            bfr[tt] = __builtin_shufflevector(b4, b4, 0, 1, 2, 3, 0, 1, 2, 3);
        }
#pragma unroll
        for (int ct = 0; ct < 4; ++ct)
#pragma unroll
            for (int rt = 0; rt < 4; ++rt)
                acc[rt][ct] = __builtin_amdgcn_mfma_scale_f32_16x16x128_f8f6f4(
                                  af[rt], bfr[ct], acc[rt][ct],
                                  4, 4,              // cbsz/blgp: A,B = fp4 e2m1
                                  0, SCALE_M4,       // scale_a = 2^-4
                                  0, SCALE_M4);      // scale_b = 2^-4
    }

    // epilogue: C/D layout col=lane&15, row=quad*4+reg (shape-determined)
    const float SC = 14.42695040888963f;   // 10 / ln(2)
    if (by == bx) {
        // diagonal block: mask diag, row sums only (col path would double count)
#pragma unroll
        for (int rt = 0; rt < 4; ++rt) {
            const int lrow = wr * 64 + rt * 16 + quad * 4;
#pragma unroll
            for (int reg = 0; reg < 4; ++reg) {
                const int lr = lrow + reg;
                float s = 0.f;
#pragma unroll
                for (int ct = 0; ct < 4; ++ct) {
                    const int lc = wc * 64 + ct * 16 + fr;
                    const float e = exp2f(acc[rt][ct][reg] * SC);
                    s += (lc == lr) ? 0.f : e;
                }
                s += __shfl_xor(s, 1);
                s += __shfl_xor(s, 2);
                s += __shfl_xor(s, 4);
                s += __shfl_xor(s, 8);
                if (fr == 0) racc[wc][lr] = s;       // unique (wc,row) writer
            }
        }
    } else {
        float csum[4] = {0.f, 0.f, 0.f, 0.f};
#pragma unroll
        for (int rt = 0; rt < 4; ++rt) {
            const int lrow = wr * 64 + rt * 16 + quad * 4;
#pragma unroll
            for (int reg = 0; reg < 4; ++reg) {
                float s = 0.f;
#pragma unroll
                for (int ct = 0; ct < 4; ++ct) {
                    const float e = exp2f(acc[rt][ct][reg] * SC);
                    s += e;
                    csum[ct] += e;
                }
                s += __shfl_xor(s, 1);
                s += __shfl_xor(s, 2);
                s += __shfl_xor(s, 4);
                s += __shfl_xor(s, 8);
                if (fr == 0) racc[wc][lrow + reg] = s;
            }
        }
#pragma unroll
        for (int ct = 0; ct < 4; ++ct) {
            float c = csum[ct];
            c += __shfl_xor(c, 16);
            c += __shfl_xor(c, 32);
            if (quad == 0) cacc[wr][wc * 64 + ct * 16 + fr] = c;  // unique writer
        }
        // pos-pair dots: local diagonal of (by, by+32) blocks; static acc indexing
        if (posdot != nullptr && bx == by + 32 && wr == wc) {
#pragma unroll
            for (int rt = 0; rt < 4; ++rt) {
                const int lrow = rt * 16 + quad * 4;
#pragma unroll
                for (int reg = 0; reg < 4; ++reg)
                    if (fr == quad * 4 + reg)        // lane's col == its row
                        posdot[arow0 + wr * 64 + lrow + reg] = acc[rt][rt][reg];
            }
        }
    }
    __syncthreads();

    // store-once partials: partials[j][i] = contribution of col-block j to rowsum[i]
    if (tid < BM) {
        partials[(size_t)bx * N2 + arow0 + tid] = racc[0][tid] + racc[1][tid];
        if (by != bx)
            partials[(size_t)by * N2 + brow0 + tid] = cacc[0][tid] + cacc[1][tid];
    }
}

// ---------------- finalize (fast): thread-per-row, 32 block atomics --------
__global__ __launch_bounds__(256) void finalize_fast(
    const float* __restrict__ partials, const float* __restrict__ posdot,
    float* __restrict__ out)
{
    const int tid = threadIdx.x;
    const int row = blockIdx.x * 256 + tid;
    float s = 0.f;
#pragma unroll 8
    for (int j = 0; j < NB; ++j) s += partials[(size_t)j * N2 + row];  // coalesced
    float nll = -10.0f * posdot[row & (HALF_N - 1)] + logf(s);
#pragma unroll
    for (int off = 32; off > 0; off >>= 1) nll += __shfl_xor(nll, off);
    __shared__ float red[4];
    if ((tid & 63) == 0) red[tid >> 6] = nll;
    __syncthreads();
    if (tid == 0)
        atomicAdd(out, (red[0] + red[1] + red[2] + red[3]) * (1.0f / N2));
}

// ---------------- finalize (fallback, if ws too small for posdot) ---------
__device__ __forceinline__ float dec_fp4(unsigned c) {
    const unsigned m = c & 7u;
    float v = (m < 4u) ? 0.5f * (float)m
            : (m == 4u) ? 2.f : (m == 5u) ? 3.f : (m == 6u) ? 4.f : 6.f;
    v *= 0.0625f;                       // 2^-4 scale
    return (c & 8u) ? -v : v;
}

__global__ __launch_bounds__(256) void finalize_slow(
    const unsigned char* __restrict__ U, const float* __restrict__ partials,
    float* __restrict__ out)
{
    const int tid  = threadIdx.x;
    const int wave = tid >> 6;
    const int lane = tid & 63;
    const int row  = blockIdx.x * 4 + wave;
    const int prow = (row + HALF_N) & (N2 - 1);

    unsigned xa = *(const unsigned*)(U + (size_t)row  * RB + lane * 4);
    unsigned ya = *(const unsigned*)(U + (size_t)prow * RB + lane * 4);
    float dot = 0.f;
#pragma unroll
    for (int j = 0; j < 8; ++j)
        dot += dec_fp4(xa >> (4 * j)) * dec_fp4(ya >> (4 * j));

    float ps = partials[(size_t)lane * N2 + row];
#pragma unroll
    for (int off = 32; off > 0; off >>= 1) {
        dot += __shfl_xor(dot, off);
        ps  += __shfl_xor(ps,  off);
    }
    __shared__ float part[4];
    if (lane == 0) part[wave] = -10.0f * dot + logf(ps);
    __syncthreads();
    if (tid == 0)
        atomicAdd(out, (part[0] + part[1] + part[2] + part[3]) * (1.0f / N2));
}

extern "C" void kernel_launch(void* const* d_in, const int* in_sizes, int n_in,
                              void* d_out, int out_size, void* d_ws, size_t ws_size,
                              hipStream_t stream)
{
    const float* z1 = (const float*)d_in[0];
    const float* z2 = (const float*)d_in[1];
    float* out      = (float*)d_out;
    unsigned char* U = (unsigned char*)d_ws;
    float* partials  = (float*)((char*)d_ws + U_BYTES);
    float* posdot    = (float*)((char*)d_ws + U_BYTES + PART_BYTES);
    const bool has_pd = ws_size >= U_BYTES + PART_BYTES + PD_BYTES;

    prep_kernel<<<N2 / 4, 256, 0, stream>>>(z1, z2, U, out);
    gram_kernel<<<NTRI, 256, 0, stream>>>(U, partials, has_pd ? posdot : nullptr);
    if (has_pd)
        finalize_fast<<<N2 / 256, 256, 0, stream>>>(partials, posdot, out);
    else
        finalize_slow<<<N2 / 4, 256, 0, stream>>>(U, partials, out);
}

// Round 12
// 97.641 us; speedup vs baseline: 1.0624x; 1.0624x over previous
//
#include <hip/hip_runtime.h>
#include <hip/hip_bf16.h>
#include <math.h>

// InfoNCE fused, symmetric-Gram, MX-fp4 (e2m1, fixed 2^-4 scales) Gram MFMA:
//   prep     : row-normalize z1|z2 -> fp4 U (2 MB), natural k-order, 2 elems/byte
//   gram     : upper-tri 128x128 tiles (r5 structure), mfma_scale 16x16x128 fp4,
//              LDS dbuf staging via global_load_lds, XOR seg swizzle;
//              exp epilogue -> partials[j][i] (store-once) + pos-pair dots
//   finalize : nll_i = -10*posdot[i%4096] + ln(sum_j partials[j][i]); mean
// [r12 = r10 verbatim: best measured config, 96.7 us total. r11 (single-barrier,
//  2 blk/CU) and r8/r9 (256-tiles) both regressed; r10 is the structural floor.]
#define N2     8192
#define HALF_N 4096
#define DD     512
#define RB     256                 // bytes per row of U (fp4: 512 * 0.5 B)
#define BM     128
#define KBT    64                  // staged bytes/row per k-tile = K=128 fp4
#define NKT    (RB / KBT)          // 4 k-tiles
#define NB     (N2 / BM)           // 64 block-rows/cols
#define NTRI   (NB * (NB + 1) / 2) // 2080 upper-tri blocks

#define U_BYTES    ((size_t)N2 * RB)          // 2 MB (fp4)
#define PART_BYTES ((size_t)NB * N2 * 4)      // 2 MB
#define PD_BYTES   ((size_t)HALF_N * 4)       // 16 KB

typedef __attribute__((ext_vector_type(4))) float f32x4;
typedef __attribute__((ext_vector_type(4))) int   i32x4;
typedef __attribute__((ext_vector_type(8))) int   i32x8;

#define SCALE_M4 0x7B7B7B7B        // E8M0 123 in every byte -> scale = 2^-4

__device__ __forceinline__ void load16_lds(const void* g, void* l) {
    // async global->LDS DMA, 16 B/lane; LDS dest = wave-uniform base + lane*16
    __builtin_amdgcn_global_load_lds(
        (const __attribute__((address_space(1))) void*)g,
        (__attribute__((address_space(3))) void*)l, 16, 0, 0);
}

// e2m1 RNE encode of t = |x|*16 (values {0,.5,1,1.5,2,3,4,6}), sign in bit 3
__device__ __forceinline__ unsigned enc_fp4(float x) {
    const float t = fabsf(x) * 16.0f;
    unsigned c = (t < 0.25f) ? 0u
               : (t < 0.75f) ? 1u
               : (t < 1.25f) ? 2u
               : (t < 1.75f) ? 3u
               : (t < 2.5f)  ? 4u
               : (t < 3.5f)  ? 5u
               : (t < 5.0f)  ? 6u : 7u;
    return c | (x < 0.0f ? 8u : 0u);
}

// ---------------- prep: normalize rows, emit fp4 (natural k-order) --------
__global__ __launch_bounds__(256) void prep_kernel(
    const float* __restrict__ z1, const float* __restrict__ z2,
    unsigned char* __restrict__ U, float* __restrict__ out)
{
    const int tid = threadIdx.x;
    if (blockIdx.x == 0 && tid == 0) out[0] = 0.0f;   // d_out re-poisoned each call

    const int wave = tid >> 6;
    const int lane = tid & 63;
    const int row  = blockIdx.x * 4 + wave;

    const float* src = (row < HALF_N) ? (z1 + (size_t)row * DD)
                                      : (z2 + (size_t)(row - HALF_N) * DD);
    float4 a = ((const float4*)src)[lane * 2 + 0];
    float4 b = ((const float4*)src)[lane * 2 + 1];
    float ss = a.x*a.x + a.y*a.y + a.z*a.z + a.w*a.w
             + b.x*b.x + b.y*b.y + b.z*b.z + b.w*b.w;
#pragma unroll
    for (int off = 32; off > 0; off >>= 1) ss += __shfl_xor(ss, off);
    const float inv = 1.0f / fmaxf(sqrtf(ss), 1e-8f);

    const float v[8] = {a.x*inv, a.y*inv, a.z*inv, a.w*inv,
                        b.x*inv, b.y*inv, b.z*inv, b.w*inv};
    unsigned pk = 0;
#pragma unroll
    for (int j = 0; j < 8; ++j)
        pk |= enc_fp4(v[j]) << (4 * j);   // elem j -> nibble j (k = lane*8 + j)
    *(unsigned*)(U + (size_t)row * RB + lane * 4) = pk;
}

// ---------------- gram: 128x128 MX-fp4 K=128, LDS staging, XOR swizzle ----
// LDS row = 64 B = 4 x 16B segs; logical seg s of row r lives at slot s^((r>>1)&3)
// -> frag b128 reads exactly 2-way bank-aliased (free), DMA dest contiguous.
__global__ __launch_bounds__(256, 3) void gram_kernel(
    const unsigned char* __restrict__ U, float* __restrict__ partials,
    float* __restrict__ posdot)
{
    __shared__ unsigned char Ash[2][BM][KBT];   // 16 KB
    __shared__ unsigned char Bsh[2][BM][KBT];   // 16 KB
    __shared__ float racc[2][BM];               // [wc][row] — unique writers
    __shared__ float cacc[2][BM];               // [wr][col] — unique writers

    const int tid  = threadIdx.x;
    const int wave = tid >> 6;
    const int lane = tid & 63;

    // linear block id -> (by, bx), by <= bx ; t0(by) = by*(129-by)/2
    const int t = blockIdx.x;
    int by = (int)((129.0 - sqrt(16641.0 - 8.0 * (double)t)) * 0.5);
    by = min(max(by, 0), NB - 1);
    while (by > 0       && t <  (by * (129 - by)) / 2) --by;
    while (by < NB - 1  && t >= ((by + 1) * (128 - by)) / 2) ++by;
    const int bx = by + (t - (by * (129 - by)) / 2);

    const int wr = wave >> 1;            // row half (0/1)
    const int wc = wave & 1;             // col half (0/1)
    const size_t arow0 = (size_t)by * BM;
    const size_t brow0 = (size_t)bx * BM;

    // staging: chunk = 16 rows x 64 B = one wave-DMA (1 KB); 8 chunks/array, 2/wave
    const int sseg = (lane & 3) ^ ((lane >> 3) & 3);   // source seg for swizzled slot

    auto stage = [&](int kt, int buf) {
        const int k0 = kt * KBT;
#pragma unroll
        for (int hh = 0; hh < 2; ++hh) {
            const int c = wave * 2 + hh;             // chunk 0..7
            const int r = c * 16 + (lane >> 2);
            load16_lds(U + (arow0 + r) * RB + k0 + sseg * 16, &Ash[buf][c * 16][0]);
            load16_lds(U + (brow0 + r) * RB + k0 + sseg * 16, &Bsh[buf][c * 16][0]);
        }
    };

    f32x4 acc[4][4];
#pragma unroll
    for (int i = 0; i < 4; ++i)
#pragma unroll
        for (int j = 0; j < 4; ++j) acc[i][j] = (f32x4){0.f, 0.f, 0.f, 0.f};

    const int fr   = lane & 15;
    const int quad = lane >> 4;
    const int sb   = (quad ^ ((fr >> 1) & 3)) * 16;  // swizzled seg byte offset

    stage(0, 0);
    __syncthreads();

    for (int kt = 0; kt < NKT; ++kt) {
        const int buf = kt & 1;
        if (kt + 1 < NKT) stage(kt + 1, buf ^ 1);    // async, drained by barrier

        i32x8 af[4], bfr[4];
#pragma unroll
        for (int tt = 0; tt < 4; ++tt) {
            i32x4 a4 = *(const i32x4*)&Ash[buf][wr * 64 + tt * 16 + fr][sb];
            i32x4 b4 = *(const i32x4*)&Bsh[buf][wc * 64 + tt * 16 + fr][sb];
            af[tt]  = __builtin_shufflevector(a4, a4, 0, 1, 2, 3, 0, 1, 2, 3);
            bfr[tt] = __builtin_shufflevector(b4, b4, 0, 1, 2, 3, 0, 1, 2, 3);
        }
#pragma unroll
        for (int ct = 0; ct < 4; ++ct)
#pragma unroll
            for (int rt = 0; rt < 4; ++rt)
                acc[rt][ct] = __builtin_amdgcn_mfma_scale_f32_16x16x128_f8f6f4(
                                  af[rt], bfr[ct], acc[rt][ct],
                                  4, 4,              // cbsz/blgp: A,B = fp4 e2m1
                                  0, SCALE_M4,       // scale_a = 2^-4
                                  0, SCALE_M4);      // scale_b = 2^-4
        __syncthreads();
    }

    // epilogue: C/D layout col=lane&15, row=quad*4+reg (shape-determined)
    const float SC = 14.42695040888963f;   // 10 / ln(2)
    if (by == bx) {
        // diagonal block: mask diag, row sums only (col path would double count)
#pragma unroll
        for (int rt = 0; rt < 4; ++rt) {
            const int lrow = wr * 64 + rt * 16 + quad * 4;
#pragma unroll
            for (int reg = 0; reg < 4; ++reg) {
                const int lr = lrow + reg;
                float s = 0.f;
#pragma unroll
                for (int ct = 0; ct < 4; ++ct) {
                    const int lc = wc * 64 + ct * 16 + fr;
                    const float e = exp2f(acc[rt][ct][reg] * SC);
                    s += (lc == lr) ? 0.f : e;
                }
                s += __shfl_xor(s, 1);
                s += __shfl_xor(s, 2);
                s += __shfl_xor(s, 4);
                s += __shfl_xor(s, 8);
                if (fr == 0) racc[wc][lr] = s;       // unique (wc,row) writer
            }
        }
    } else {
        float csum[4] = {0.f, 0.f, 0.f, 0.f};
#pragma unroll
        for (int rt = 0; rt < 4; ++rt) {
            const int lrow = wr * 64 + rt * 16 + quad * 4;
#pragma unroll
            for (int reg = 0; reg < 4; ++reg) {
                float s = 0.f;
#pragma unroll
                for (int ct = 0; ct < 4; ++ct) {
                    const float e = exp2f(acc[rt][ct][reg] * SC);
                    s += e;
                    csum[ct] += e;
                }
                s += __shfl_xor(s, 1);
                s += __shfl_xor(s, 2);
                s += __shfl_xor(s, 4);
                s += __shfl_xor(s, 8);
                if (fr == 0) racc[wc][lrow + reg] = s;
            }
        }
#pragma unroll
        for (int ct = 0; ct < 4; ++ct) {
            float c = csum[ct];
            c += __shfl_xor(c, 16);
            c += __shfl_xor(c, 32);
            if (quad == 0) cacc[wr][wc * 64 + ct * 16 + fr] = c;  // unique writer
        }
        // pos-pair dots: local diagonal of (by, by+32) blocks; static acc indexing
        if (posdot != nullptr && bx == by + 32 && wr == wc) {
#pragma unroll
            for (int rt = 0; rt < 4; ++rt) {
                const int lrow = rt * 16 + quad * 4;
#pragma unroll
                for (int reg = 0; reg < 4; ++reg)
                    if (fr == quad * 4 + reg)        // lane's col == its row
                        posdot[arow0 + wr * 64 + lrow + reg] = acc[rt][rt][reg];
            }
        }
    }
    __syncthreads();

    // store-once partials: partials[j][i] = contribution of col-block j to rowsum[i]
    if (tid < BM) {
        partials[(size_t)bx * N2 + arow0 + tid] = racc[0][tid] + racc[1][tid];
        if (by != bx)
            partials[(size_t)by * N2 + brow0 + tid] = cacc[0][tid] + cacc[1][tid];
    }
}

// ---------------- finalize (fast): thread-per-row, 32 block atomics --------
__global__ __launch_bounds__(256) void finalize_fast(
    const float* __restrict__ partials, const float* __restrict__ posdot,
    float* __restrict__ out)
{
    const int tid = threadIdx.x;
    const int row = blockIdx.x * 256 + tid;
    float s = 0.f;
#pragma unroll 8
    for (int j = 0; j < NB; ++j) s += partials[(size_t)j * N2 + row];  // coalesced
    float nll = -10.0f * posdot[row & (HALF_N - 1)] + logf(s);
#pragma unroll
    for (int off = 32; off > 0; off >>= 1) nll += __shfl_xor(nll, off);
    __shared__ float red[4];
    if ((tid & 63) == 0) red[tid >> 6] = nll;
    __syncthreads();
    if (tid == 0)
        atomicAdd(out, (red[0] + red[1] + red[2] + red[3]) * (1.0f / N2));
}

// ---------------- finalize (fallback, if ws too small for posdot) ---------
__device__ __forceinline__ float dec_fp4(unsigned c) {
    const unsigned m = c & 7u;
    float v = (m < 4u) ? 0.5f * (float)m
            : (m == 4u) ? 2.f : (m == 5u) ? 3.f : (m == 6u) ? 4.f : 6.f;
    v *= 0.0625f;                       // 2^-4 scale
    return (c & 8u) ? -v : v;
}

__global__ __launch_bounds__(256) void finalize_slow(
    const unsigned char* __restrict__ U, const float* __restrict__ partials,
    float* __restrict__ out)
{
    const int tid  = threadIdx.x;
    const int wave = tid >> 6;
    const int lane = tid & 63;
    const int row  = blockIdx.x * 4 + wave;
    const int prow = (row + HALF_N) & (N2 - 1);

    unsigned xa = *(const unsigned*)(U + (size_t)row  * RB + lane * 4);
    unsigned ya = *(const unsigned*)(U + (size_t)prow * RB + lane * 4);
    float dot = 0.f;
#pragma unroll
    for (int j = 0; j < 8; ++j)
        dot += dec_fp4(xa >> (4 * j)) * dec_fp4(ya >> (4 * j));

    float ps = partials[(size_t)lane * N2 + row];
#pragma unroll
    for (int off = 32; off > 0; off >>= 1) {
        dot += __shfl_xor(dot, off);
        ps  += __shfl_xor(ps,  off);
    }
    __shared__ float part[4];
    if (lane == 0) part[wave] = -10.0f * dot + logf(ps);
    __syncthreads();
    if (tid == 0)
        atomicAdd(out, (part[0] + part[1] + part[2] + part[3]) * (1.0f / N2));
}

extern "C" void kernel_launch(void* const* d_in, const int* in_sizes, int n_in,
                              void* d_out, int out_size, void* d_ws, size_t ws_size,
                              hipStream_t stream)
{
    const float* z1 = (const float*)d_in[0];
    const float* z2 = (const float*)d_in[1];
    float* out      = (float*)d_out;
    unsigned char* U = (unsigned char*)d_ws;
    float* partials  = (float*)((char*)d_ws + U_BYTES);
    float* posdot    = (float*)((char*)d_ws + U_BYTES + PART_BYTES);
    const bool has_pd = ws_size >= U_BYTES + PART_BYTES + PD_BYTES;

    prep_kernel<<<N2 / 4, 256, 0, stream>>>(z1, z2, U, out);
    gram_kernel<<<NTRI, 256, 0, stream>>>(U, partials, has_pd ? posdot : nullptr);
    if (has_pd)
        finalize_fast<<<N2 / 256, 256, 0, stream>>>(partials, posdot, out);
    else
        finalize_slow<<<N2 / 4, 256, 0, stream>>>(U, partials, out);
}